// Round 1
// baseline (5765.515 us; speedup 1.0000x reference)
//
#include <hip/hip_runtime.h>

#define BATCH 65536
#define NSP 26
#define NROW 27
#define EMBD 128
#define TOPIN 506
#define VOCAB_MASK (1048576 - 1)

// ---------------------------------------------------------------------------
// Generic fp32 GEMM: C = act(A @ W + bias)
// A: MxK row-major (ld=K), W: KxN row-major (ld=N), C: MxN row-major (ld=N)
// 128x128 tile, K-step 16, 256 threads, 8x8 microtile per thread.
// M must be a multiple of 128, N a multiple of 128; K arbitrary (guarded).
// ---------------------------------------------------------------------------
__global__ __launch_bounds__(256) void gemm_bias_act(
    const float* __restrict__ A, const float* __restrict__ W,
    const float* __restrict__ bias, float* __restrict__ C,
    int M, int K, int N, int do_relu)
{
    __shared__ float As[16][132];   // As[k][m]  (A tile stored transposed)
    __shared__ float Ws[16][132];   // Ws[k][n]
    const int tid = threadIdx.x;
    const int tx = tid & 15;        // col group (8 cols each)
    const int ty = tid >> 4;        // row group (8 rows each)
    const int m0 = blockIdx.x * 128;
    const int n0 = blockIdx.y * 128;

    float acc[8][8];
#pragma unroll
    for (int i = 0; i < 8; ++i)
#pragma unroll
        for (int j = 0; j < 8; ++j) acc[i][j] = 0.f;

    for (int k0 = 0; k0 < K; k0 += 16) {
        // ---- stage A tile: rows m0..m0+127, k = k0..k0+15 -> As[k][row]
        {
            const int row = tid >> 1;
            const int kk = (tid & 1) * 8;
            const float* ap = A + (size_t)(m0 + row) * K + k0 + kk;
#pragma unroll
            for (int i = 0; i < 8; ++i) {
                const int k = k0 + kk + i;
                As[kk + i][row] = (k < K) ? ap[i] : 0.f;
            }
        }
        // ---- stage W tile: k = k0..k0+15, cols n0..n0+127 -> Ws[k][col]
        {
            const int k = tid >> 4;
            const int col = (tid & 15) * 8;
            const float* wp = W + (size_t)(k0 + k) * N + n0 + col;
            const bool kok = (k0 + k) < K;
#pragma unroll
            for (int i = 0; i < 8; ++i)
                Ws[k][col + i] = kok ? wp[i] : 0.f;
        }
        __syncthreads();

#pragma unroll
        for (int k = 0; k < 16; ++k) {
            float a[8], w[8];
            *(float4*)&a[0] = *(const float4*)&As[k][ty * 8];
            *(float4*)&a[4] = *(const float4*)&As[k][ty * 8 + 4];
            *(float4*)&w[0] = *(const float4*)&Ws[k][tx * 8];
            *(float4*)&w[4] = *(const float4*)&Ws[k][tx * 8 + 4];
#pragma unroll
            for (int i = 0; i < 8; ++i)
#pragma unroll
                for (int j = 0; j < 8; ++j)
                    acc[i][j] = fmaf(a[i], w[j], acc[i][j]);
        }
        __syncthreads();
    }

    // ---- epilogue: bias + optional relu
#pragma unroll
    for (int i = 0; i < 8; ++i) {
        const int m = m0 + ty * 8 + i;
        float* cp = C + (size_t)m * N + n0 + tx * 8;
#pragma unroll
        for (int j = 0; j < 8; ++j) {
            float v = acc[i][j] + bias[n0 + tx * 8 + j];
            if (do_relu) v = fmaxf(v, 0.f);
            cp[j] = v;
        }
    }
}

// ---------------------------------------------------------------------------
// Interaction: per sample b, combined = [h(128) ; emb[idx[b][0..25]] ] (27x128)
// Gram = combined @ combined^T, write h (128) + triu(Gram) (378) -> top[b][506]
// One wave per sample, 4 samples per 256-thread block.
// LDS layout: V[wave][k][row] (k-major so 4-row column slices are b128 reads)
// Lane l: tile t = l/2 (28 upper 4x4 tiles of the 28x28-padded Gram),
//         k-half = l&1; halves combined with shfl_xor(1).
// ---------------------------------------------------------------------------
__global__ __launch_bounds__(256) void interact_kernel(
    const float* __restrict__ H, const int* __restrict__ sidx,
    const float* __restrict__ emb, float* __restrict__ top)
{
    __shared__ float V[4][EMBD][28];   // 57344 B
    const int wave = threadIdx.x >> 6;
    const int lane = threadIdx.x & 63;
    const int b = blockIdx.x * 4 + wave;
    float* tb = top + (size_t)b * TOPIN;

    // ---- stage 27 rows (h + 26 gathered emb rows), transposed into V
    for (int t = lane; t < NROW * (EMBD / 4); t += 64) {
        const int row = t >> 5;            // 32 float4 chunks per row
        const int ch = (t & 31) * 4;
        const float* src;
        if (row == 0) {
            src = H + (size_t)b * EMBD + ch;
        } else {
            const int ix = sidx[(size_t)b * NSP + (row - 1)] & VOCAB_MASK;
            src = emb + (size_t)ix * EMBD + ch;
        }
        const float4 v = *(const float4*)src;
        V[wave][ch + 0][row] = v.x;
        V[wave][ch + 1][row] = v.y;
        V[wave][ch + 2][row] = v.z;
        V[wave][ch + 3][row] = v.w;
        if (row == 0) {   // top[b][0:128] = h  (LD 506 -> scalar stores)
            tb[ch + 0] = v.x; tb[ch + 1] = v.y;
            tb[ch + 2] = v.z; tb[ch + 3] = v.w;
        }
    }
    __syncthreads();

    const int t = lane >> 1;
    const int kh = lane & 1;
    const bool active = (t < 28);
    int tr = 0, tc = 0;
    if (active) {                          // enumerate upper 4x4 tiles row-major
        int rem = t;
        while (rem >= 7 - tr) { rem -= 7 - tr; ++tr; }
        tc = tr + rem;
    }
    float acc[4][4];
#pragma unroll
    for (int i = 0; i < 4; ++i)
#pragma unroll
        for (int j = 0; j < 4; ++j) acc[i][j] = 0.f;

    if (active) {
        const int r0 = 4 * tr, c0 = 4 * tc;
        for (int kk = 0; kk < 64; ++kk) {
            const int k = kh * 64 + kk;
            const float4 a = *(const float4*)&V[wave][k][r0];
            const float4 c = *(const float4*)&V[wave][k][c0];
            const float av[4] = {a.x, a.y, a.z, a.w};
            const float cv[4] = {c.x, c.y, c.z, c.w};
#pragma unroll
            for (int i = 0; i < 4; ++i)
#pragma unroll
                for (int j = 0; j < 4; ++j)
                    acc[i][j] = fmaf(av[i], cv[j], acc[i][j]);
        }
        // combine the two k-halves (lane pairs 2t, 2t+1)
#pragma unroll
        for (int i = 0; i < 4; ++i)
#pragma unroll
            for (int j = 0; j < 4; ++j)
                acc[i][j] += __shfl_xor(acc[i][j], 1);

        if (kh == 0) {
#pragma unroll
            for (int i = 0; i < 4; ++i) {
                const int r = r0 + i;
                if (r >= NROW) continue;
                // triu linear index: rowstart(r) = 27r - r(r-1)/2 ; p = rowstart + (c - r)
                const int base = 128 + r * NROW - (r * (r - 1)) / 2 - r;
#pragma unroll
                for (int j = 0; j < 4; ++j) {
                    const int c = c0 + j;
                    if (c < r || c >= NROW) continue;
                    tb[base + c] = acc[i][j];
                }
            }
        }
    }
}

// ---------------------------------------------------------------------------
// Final layer: out[b] = dot(A[b][0:256], w) + bias   (no relu)
// One wave per row; 4 rows per block.
// ---------------------------------------------------------------------------
__global__ __launch_bounds__(256) void final_dot(
    const float* __restrict__ A, const float* __restrict__ w,
    const float* __restrict__ bias, float* __restrict__ out)
{
    const int wave = threadIdx.x >> 6;
    const int lane = threadIdx.x & 63;
    const int b = blockIdx.x * 4 + wave;
    const float4 av = *(const float4*)(A + (size_t)b * 256 + lane * 4);
    const float4 wv = *(const float4*)(w + lane * 4);
    float s = av.x * wv.x + av.y * wv.y + av.z * wv.z + av.w * wv.w;
#pragma unroll
    for (int off = 32; off > 0; off >>= 1) s += __shfl_down(s, off);
    if (lane == 0) out[b] = s + bias[0];
}

// ---------------------------------------------------------------------------
extern "C" void kernel_launch(void* const* d_in, const int* in_sizes, int n_in,
                              void* d_out, int out_size, void* d_ws, size_t ws_size,
                              hipStream_t stream)
{
    const float* dense = (const float*)d_in[0];
    const int*   sidx  = (const int*)d_in[1];
    const float* emb   = (const float*)d_in[2];
    const float* bw0 = (const float*)d_in[3],  *bb0 = (const float*)d_in[4];
    const float* bw1 = (const float*)d_in[5],  *bb1 = (const float*)d_in[6];
    const float* bw2 = (const float*)d_in[7],  *bb2 = (const float*)d_in[8];
    const float* tw0 = (const float*)d_in[9],  *tb0 = (const float*)d_in[10];
    const float* tw1 = (const float*)d_in[11], *tb1 = (const float*)d_in[12];
    const float* tw2 = (const float*)d_in[13], *tb2 = (const float*)d_in[14];
    const float* tw3 = (const float*)d_in[15], *tb3 = (const float*)d_in[16];
    const float* tw4 = (const float*)d_in[17], *tb4 = (const float*)d_in[18];
    float* out = (float*)d_out;

    // workspace layout: X (65536x1024 f32), Y (65536x1024 f32), H (65536x128 f32)
    char* ws = (char*)d_ws;
    const size_t BIG = (size_t)BATCH * 1024 * sizeof(float);   // 268 MB
    float* X  = (float*)(ws);
    float* Y  = (float*)(ws + BIG);
    float* Hb = (float*)(ws + 2 * BIG);

    const dim3 blk(256);

    // bottom MLP: dense(13) -> 512 -> 256 -> 128, relu each
    gemm_bias_act<<<dim3(512, 4), blk, 0, stream>>>(dense, bw0, bb0, X,  BATCH, 13,  512, 1);
    gemm_bias_act<<<dim3(512, 2), blk, 0, stream>>>(X,     bw1, bb1, Y,  BATCH, 512, 256, 1);
    gemm_bias_act<<<dim3(512, 1), blk, 0, stream>>>(Y,     bw2, bb2, Hb, BATCH, 256, 128, 1);

    // interaction: h + 26 emb rows -> Gram triu -> top_in (506) into X
    interact_kernel<<<dim3(BATCH / 4), blk, 0, stream>>>(Hb, sidx, emb, X);

    // top MLP: 506 -> 1024 -> 1024 -> 512 -> 256 -> 1
    gemm_bias_act<<<dim3(512, 8), blk, 0, stream>>>(X, tw0, tb0, Y, BATCH, 506,  1024, 1);
    gemm_bias_act<<<dim3(512, 8), blk, 0, stream>>>(Y, tw1, tb1, X, BATCH, 1024, 1024, 1);
    gemm_bias_act<<<dim3(512, 4), blk, 0, stream>>>(X, tw2, tb2, Y, BATCH, 1024, 512,  1);
    gemm_bias_act<<<dim3(512, 2), blk, 0, stream>>>(Y, tw3, tb3, X, BATCH, 512,  256,  1);
    final_dot<<<dim3(BATCH / 4), blk, 0, stream>>>(X, tw4, tb4, out);
}

// Round 2
// 2623.756 us; speedup vs baseline: 2.1974x; 2.1974x over previous
//
#include <hip/hip_runtime.h>

#define BATCH 65536
#define NSP 26
#define NROW 27
#define VOCAB_MASK (1048576 - 1)

typedef unsigned short u16;
typedef unsigned int u32;
typedef float f32x4 __attribute__((ext_vector_type(4)));
typedef __bf16 bf16x8 __attribute__((ext_vector_type(8)));

__device__ __forceinline__ u16 f2bf(float f) {
    u32 u = __float_as_uint(f);
    u = (u + 0x7FFFu + ((u >> 16) & 1u)) >> 16;
    return (u16)u;
}
__device__ __forceinline__ float bf2f(u16 h) { return __uint_as_float(((u32)h) << 16); }
__device__ __forceinline__ void fsplit(float x, u16& hi, u16& lo) {
    hi = f2bf(x);
    lo = f2bf(x - bf2f(hi));
}

// async global->LDS, 16B per lane; LDS dest = wave-uniform base + lane*16
#define GLD16(gp, lp) __builtin_amdgcn_global_load_lds( \
    (const __attribute__((address_space(1))) u32*)(gp), \
    (__attribute__((address_space(3))) u32*)(lp), 16, 0, 0)

// ---------------------------------------------------------------------------
// Hi/lo bf16 MFMA GEMM.  C = act(A@W + bias), A=Ahi+Alo, W=Whi+Wlo.
// Storage layout everywhere: K8-chunked  arr[k/8][row][8]  (16B per row-chunk).
//   A: [K/8][M][8] (row=m), W: [K/8][N][8] (row=n, i.e. W^T), C: [N/8][M][8].
// 128x128 tile, 256 thr = 4 waves, each wave 64x64 via 4x4 mfma_16x16x32 tiles.
// 3 MFMAs per tile per k-step: Ahi*Whi + Ahi*Wlo + Alo*Whi  (~2^-16 rel err).
// ---------------------------------------------------------------------------
__global__ __launch_bounds__(256) void gemm_mfma(
    const u16* __restrict__ Ahi, const u16* __restrict__ Alo,
    const u16* __restrict__ Whi, const u16* __restrict__ Wlo,
    const float* __restrict__ bias,
    u16* __restrict__ Chi, u16* __restrict__ Clo,
    int M, int K, int N, int relu)
{
    __shared__ u16 sAh[4096], sAl[4096], sWh[4096], sWl[4096];   // 8KB each
    const int tid = threadIdx.x;
    const int w = tid >> 6, lane = tid & 63;
    const int wr = w >> 1, wc = w & 1;          // wave's 64x64 quadrant
    const int m0 = blockIdx.y * 128, n0 = blockIdx.x * 128;
    const int ml = lane & 15, q = lane >> 4;

    f32x4 acc[4][4];
#pragma unroll
    for (int i = 0; i < 4; ++i)
#pragma unroll
        for (int j = 0; j < 4; ++j)
#pragma unroll
            for (int r = 0; r < 4; ++r) acc[i][j][r] = 0.f;

    const int nIter = K >> 5;                    // BK = 32 = 4 chunks of 8
    for (int it = 0; it < nIter; ++it) {
        const int c = it * 4 + w;                // this wave stages chunk c
#pragma unroll
        for (int h = 0; h < 2; ++h) {            // 64 rows per instruction
            const size_t ga = ((size_t)c * M + m0 + h * 64 + lane) * 8;
            const size_t gw = ((size_t)c * N + n0 + h * 64 + lane) * 8;
            GLD16(Ahi + ga, sAh + w * 1024 + h * 512);
            GLD16(Alo + ga, sAl + w * 1024 + h * 512);
            GLD16(Whi + gw, sWh + w * 1024 + h * 512);
            GLD16(Wlo + gw, sWl + w * 1024 + h * 512);
        }
        __syncthreads();

        // fragment loads: lane (ml, q) reads row (tileBase+ml), k-chunk q -> b128
        const int ab = q * 1024 + wr * 512 + ml * 8;
        const int bb = q * 1024 + wc * 512 + ml * 8;
        bf16x8 ah[4], al[4], bh[4], bl[4];
#pragma unroll
        for (int t = 0; t < 4; ++t) {
            ah[t] = *(const bf16x8*)&sAh[ab + t * 128];
            al[t] = *(const bf16x8*)&sAl[ab + t * 128];
            bh[t] = *(const bf16x8*)&sWh[bb + t * 128];
            bl[t] = *(const bf16x8*)&sWl[bb + t * 128];
        }
#pragma unroll
        for (int i = 0; i < 4; ++i)
#pragma unroll
            for (int j = 0; j < 4; ++j) {
                f32x4 a = acc[i][j];
                a = __builtin_amdgcn_mfma_f32_16x16x32_bf16(al[i], bh[j], a, 0, 0, 0);
                a = __builtin_amdgcn_mfma_f32_16x16x32_bf16(ah[i], bl[j], a, 0, 0, 0);
                a = __builtin_amdgcn_mfma_f32_16x16x32_bf16(ah[i], bh[j], a, 0, 0, 0);
                acc[i][j] = a;
            }
        __syncthreads();
    }

    // epilogue: bias + relu, split to hi/lo, store K8-chunked [N/8][M][8]
#pragma unroll
    for (int j = 0; j < 4; ++j) {
        const int n = n0 + wc * 64 + j * 16 + ml;
        const float bs = bias[n];
        const size_t cb = (size_t)(n >> 3) * M * 8 + (n & 7);
#pragma unroll
        for (int i = 0; i < 4; ++i) {
            const int mbase = m0 + wr * 64 + i * 16 + q * 4;
#pragma unroll
            for (int r = 0; r < 4; ++r) {
                float x = acc[i][j][r] + bs;
                if (relu) x = fmaxf(x, 0.f);
                u16 hi, lo; fsplit(x, hi, lo);
                const size_t off = cb + (size_t)(mbase + r) * 8;
                Chi[off] = hi; Clo[off] = lo;
            }
        }
    }
}

// ---------------------------------------------------------------------------
// fp32 KxN weight -> K8-chunked W^T hi/lo  ([Kpad/8][N][8]), zero pad k>=Kreal
// ---------------------------------------------------------------------------
__global__ void conv_w(const float* __restrict__ W, u16* __restrict__ Whi,
                       u16* __restrict__ Wlo, int Kreal, int Kpad, int N)
{
    const int idx = blockIdx.x * 256 + threadIdx.x;   // one per (c, n)
    if (idx >= (Kpad >> 3) * N) return;
    const int c = idx / N, n = idx - c * N;
#pragma unroll
    for (int j = 0; j < 8; ++j) {
        const int k = c * 8 + j;
        const float x = (k < Kreal) ? W[(size_t)k * N + n] : 0.f;
        u16 hi, lo; fsplit(x, hi, lo);
        Whi[(size_t)idx * 8 + j] = hi;
        Wlo[(size_t)idx * 8 + j] = lo;
    }
}

// dense (BATCH x 13 fp32) -> K8-chunked hi/lo [4][BATCH][8], zero pad k>=13
__global__ void conv_dense(const float* __restrict__ dense,
                           u16* __restrict__ Dhi, u16* __restrict__ Dlo)
{
    const int m = blockIdx.x * 256 + threadIdx.x;
    float v[13];
#pragma unroll
    for (int j = 0; j < 13; ++j) v[j] = dense[(size_t)m * 13 + j];
#pragma unroll
    for (int cc = 0; cc < 4; ++cc) {
        const size_t base = ((size_t)cc * BATCH + m) * 8;
#pragma unroll
        for (int j = 0; j < 8; ++j) {
            const int k = cc * 8 + j;
            const float x = (k < 13) ? v[k] : 0.f;
            u16 hi, lo; fsplit(x, hi, lo);
            Dhi[base + j] = hi; Dlo[base + j] = lo;
        }
    }
}

// ---------------------------------------------------------------------------
// Interaction. X is the top-input buffer in K8-chunked hi/lo layout (K=512):
// chunks 0..15 already hold h (written by bottom-MLP L2). This kernel reads h
// (hi+lo), gathers 26 emb rows (fp32), computes the 27x27 Gram in fp32, and
// writes triu -> chunks 16..63 (k=128..505) + zero pad (k=506..511).
// One wave per sample, 4 samples/block. V[wave][k][row], k-major.
// ---------------------------------------------------------------------------
__global__ __launch_bounds__(256) void interact_kernel(
    u16* __restrict__ Xhi, u16* __restrict__ Xlo,
    const int* __restrict__ sidx, const float* __restrict__ emb)
{
    __shared__ float V[4][128][28];   // 57344 B
    const int wave = threadIdx.x >> 6, lane = threadIdx.x & 63;
    const int b = blockIdx.x * 4 + wave;

    for (int t = lane; t < NROW * 32; t += 64) {
        const int row = t >> 5;
        const int ch = (t & 31) * 4;            // k = ch..ch+3
        float4 v;
        if (row == 0) {
            const size_t base = ((size_t)(ch >> 3) * BATCH + b) * 8 + (ch & 7);
            const ushort4 h4 = *(const ushort4*)&Xhi[base];
            const ushort4 l4 = *(const ushort4*)&Xlo[base];
            v.x = bf2f(h4.x) + bf2f(l4.x);
            v.y = bf2f(h4.y) + bf2f(l4.y);
            v.z = bf2f(h4.z) + bf2f(l4.z);
            v.w = bf2f(h4.w) + bf2f(l4.w);
        } else {
            const int ix = sidx[(size_t)b * NSP + (row - 1)] & VOCAB_MASK;
            v = *(const float4*)(emb + (size_t)ix * 128 + ch);
        }
        V[wave][ch + 0][row] = v.x;
        V[wave][ch + 1][row] = v.y;
        V[wave][ch + 2][row] = v.z;
        V[wave][ch + 3][row] = v.w;
    }
    __syncthreads();

    const int t = lane >> 1;
    const int kh = lane & 1;
    const bool active = (t < 28);
    int tr = 0, tc = 0;
    if (active) {                               // upper 4x4 tiles, row-major
        int rem = t;
        while (rem >= 7 - tr) { rem -= 7 - tr; ++tr; }
        tc = tr + rem;
    }
    float acc[4][4];
#pragma unroll
    for (int i = 0; i < 4; ++i)
#pragma unroll
        for (int j = 0; j < 4; ++j) acc[i][j] = 0.f;

    if (active) {
        const int r0 = 4 * tr, c0 = 4 * tc;
        for (int kk = 0; kk < 64; ++kk) {
            const int k = kh * 64 + kk;
            const float4 a = *(const float4*)&V[wave][k][r0];
            const float4 c = *(const float4*)&V[wave][k][c0];
            const float av[4] = {a.x, a.y, a.z, a.w};
            const float cv[4] = {c.x, c.y, c.z, c.w};
#pragma unroll
            for (int i = 0; i < 4; ++i)
#pragma unroll
                for (int j = 0; j < 4; ++j)
                    acc[i][j] = fmaf(av[i], cv[j], acc[i][j]);
        }
#pragma unroll
        for (int i = 0; i < 4; ++i)
#pragma unroll
            for (int j = 0; j < 4; ++j)
                acc[i][j] += __shfl_xor(acc[i][j], 1);

        if (kh == 0) {
#pragma unroll
            for (int i = 0; i < 4; ++i) {
                const int r = r0 + i;
                if (r >= NROW) continue;
                const int kb = 128 + r * NROW - (r * (r - 1)) / 2 - r;
#pragma unroll
                for (int j = 0; j < 4; ++j) {
                    const int c = c0 + j;
                    if (c < r || c >= NROW) continue;
                    const int k = kb + c;
                    u16 hi, lo; fsplit(acc[i][j], hi, lo);
                    const size_t off = ((size_t)(k >> 3) * BATCH + b) * 8 + (k & 7);
                    Xhi[off] = hi; Xlo[off] = lo;
                }
            }
        }
    }
    if (lane == 0) {                            // zero pad k = 506..511
        for (int k = 506; k < 512; ++k) {
            const size_t off = ((size_t)(k >> 3) * BATCH + b) * 8 + (k & 7);
            Xhi[off] = 0; Xlo[off] = 0;
        }
    }
}

// ---------------------------------------------------------------------------
// Final layer: out[b] = dot(A[b][:256], w) + bias.  A is K8-chunked hi/lo.
// One wave per sample: lanes 0..31 do hi chunks, 32..63 lo chunks.
// ---------------------------------------------------------------------------
__global__ __launch_bounds__(256) void final_dot(
    const u16* __restrict__ Ahi, const u16* __restrict__ Alo,
    const float* __restrict__ wv, const float* __restrict__ bias,
    float* __restrict__ out)
{
    const int wave = threadIdx.x >> 6, lane = threadIdx.x & 63;
    const int b = blockIdx.x * 4 + wave;
    const int c = lane & 31;
    const u16* src = (lane >= 32) ? Alo : Ahi;
    const size_t base = ((size_t)c * BATCH + b) * 8;
    float s = 0.f;
#pragma unroll
    for (int j = 0; j < 8; ++j) s += bf2f(src[base + j]) * wv[c * 8 + j];
#pragma unroll
    for (int off = 32; off > 0; off >>= 1) s += __shfl_down(s, off);
    if (lane == 0) out[b] = s + bias[0];
}

// ---------------------------------------------------------------------------
extern "C" void kernel_launch(void* const* d_in, const int* in_sizes, int n_in,
                              void* d_out, int out_size, void* d_ws, size_t ws_size,
                              hipStream_t stream)
{
    const float* dense = (const float*)d_in[0];
    const int*   sidx  = (const int*)d_in[1];
    const float* emb   = (const float*)d_in[2];
    const float* bw0 = (const float*)d_in[3],  *bb0 = (const float*)d_in[4];
    const float* bw1 = (const float*)d_in[5],  *bb1 = (const float*)d_in[6];
    const float* bw2 = (const float*)d_in[7],  *bb2 = (const float*)d_in[8];
    const float* tw0 = (const float*)d_in[9],  *tb0 = (const float*)d_in[10];
    const float* tw1 = (const float*)d_in[11], *tb1 = (const float*)d_in[12];
    const float* tw2 = (const float*)d_in[13], *tb2 = (const float*)d_in[14];
    const float* tw3 = (const float*)d_in[15], *tb3 = (const float*)d_in[16];
    const float* tw4 = (const float*)d_in[17], *tb4 = (const float*)d_in[18];
    float* out = (float*)d_out;

    // ---- workspace carve-up (~555 MB)
    char* p = (char*)d_ws;
    const size_t ACT = (size_t)BATCH * 1024 * sizeof(u16);   // 134 MB
    u16* Xhi = (u16*)p; p += ACT;
    u16* Xlo = (u16*)p; p += ACT;
    u16* Yhi = (u16*)p; p += ACT;
    u16* Ylo = (u16*)p; p += ACT;
    u16* D0hi = (u16*)p; p += (size_t)BATCH * 32 * sizeof(u16);
    u16* D0lo = (u16*)p; p += (size_t)BATCH * 32 * sizeof(u16);
    auto alloc_w = [&](size_t elems, u16** hi, u16** lo) {
        *hi = (u16*)p; p += elems * sizeof(u16);
        *lo = (u16*)p; p += elems * sizeof(u16);
    };
    u16 *W0h,*W0l,*W1h,*W1l,*W2h,*W2l,*T0h,*T0l,*T1h,*T1l,*T2h,*T2l,*T3h,*T3l;
    alloc_w(32 * 512, &W0h, &W0l);
    alloc_w(512 * 256, &W1h, &W1l);
    alloc_w(256 * 128, &W2h, &W2l);
    alloc_w(512 * 1024, &T0h, &T0l);
    alloc_w(1024 * 1024, &T1h, &T1l);
    alloc_w(1024 * 512, &T2h, &T2l);
    alloc_w(512 * 256, &T3h, &T3l);

    const dim3 blk(256);
    auto cwg = [](int kpad, int n) { return dim3(((kpad >> 3) * n + 255) / 256); };

    // ---- convert inputs to hi/lo chunked bf16
    conv_dense<<<BATCH / 256, blk, 0, stream>>>(dense, D0hi, D0lo);
    conv_w<<<cwg(32, 512),    blk, 0, stream>>>(bw0, W0h, W0l, 13,   32,   512);
    conv_w<<<cwg(512, 256),   blk, 0, stream>>>(bw1, W1h, W1l, 512,  512,  256);
    conv_w<<<cwg(256, 128),   blk, 0, stream>>>(bw2, W2h, W2l, 256,  256,  128);
    conv_w<<<cwg(512, 1024),  blk, 0, stream>>>(tw0, T0h, T0l, 506,  512,  1024);
    conv_w<<<cwg(1024, 1024), blk, 0, stream>>>(tw1, T1h, T1l, 1024, 1024, 1024);
    conv_w<<<cwg(1024, 512),  blk, 0, stream>>>(tw2, T2h, T2l, 1024, 1024, 512);
    conv_w<<<cwg(512, 256),   blk, 0, stream>>>(tw3, T3h, T3l, 512,  512,  256);

    // ---- bottom MLP (13->512->256->128); L2 lands in X chunks 0..15 (= h)
    gemm_mfma<<<dim3(4, 512), blk, 0, stream>>>(D0hi, D0lo, W0h, W0l, bb0, Xhi, Xlo, BATCH, 32,  512, 1);
    gemm_mfma<<<dim3(2, 512), blk, 0, stream>>>(Xhi, Xlo, W1h, W1l, bb1, Yhi, Ylo, BATCH, 512, 256, 1);
    gemm_mfma<<<dim3(1, 512), blk, 0, stream>>>(Yhi, Ylo, W2h, W2l, bb2, Xhi, Xlo, BATCH, 256, 128, 1);

    // ---- interaction fills X chunks 16..63 (triu + pad)
    interact_kernel<<<dim3(BATCH / 4), blk, 0, stream>>>(Xhi, Xlo, sidx, emb);

    // ---- top MLP (506(512)->1024->1024->512->256->1)
    gemm_mfma<<<dim3(8, 512), blk, 0, stream>>>(Xhi, Xlo, T0h, T0l, tb0, Yhi, Ylo, BATCH, 512,  1024, 1);
    gemm_mfma<<<dim3(8, 512), blk, 0, stream>>>(Yhi, Ylo, T1h, T1l, tb1, Xhi, Xlo, BATCH, 1024, 1024, 1);
    gemm_mfma<<<dim3(4, 512), blk, 0, stream>>>(Xhi, Xlo, T2h, T2l, tb2, Yhi, Ylo, BATCH, 1024, 512,  1);
    gemm_mfma<<<dim3(2, 512), blk, 0, stream>>>(Yhi, Ylo, T3h, T3l, tb3, Xhi, Xlo, BATCH, 512,  256,  1);
    final_dot<<<dim3(BATCH / 4), blk, 0, stream>>>(Xhi, Xlo, tw4, tb4, out);
}

// Round 3
// 2236.992 us; speedup vs baseline: 2.5774x; 1.1729x over previous
//
#include <hip/hip_runtime.h>

#define BATCH 65536
#define NSP 26
#define NROW 27
#define VOCAB_MASK (1048576 - 1)

typedef unsigned short u16;
typedef unsigned int u32;
typedef float f32x4 __attribute__((ext_vector_type(4)));
typedef float f32x16 __attribute__((ext_vector_type(16)));
typedef __bf16 bf16x8 __attribute__((ext_vector_type(8)));

__device__ __forceinline__ u16 f2bf(float f) {
    u32 u = __float_as_uint(f);
    u = (u + 0x7FFFu + ((u >> 16) & 1u)) >> 16;
    return (u16)u;
}
__device__ __forceinline__ float bf2f(u16 h) { return __uint_as_float(((u32)h) << 16); }
__device__ __forceinline__ void fsplit(float x, u16& hi, u16& lo) {
    hi = f2bf(x);
    lo = f2bf(x - bf2f(hi));
}
__device__ __forceinline__ __bf16 u2b(u16 h) { union { u16 u; __bf16 b; } c; c.u = h; return c.b; }

// async global->LDS, 16B per lane; LDS dest = wave-uniform base + lane*16
#define GLD16(gp, lp) __builtin_amdgcn_global_load_lds( \
    (const __attribute__((address_space(1))) u32*)(gp), \
    (__attribute__((address_space(3))) u32*)(lp), 16, 0, 0)

// ---------------------------------------------------------------------------
// Hi/lo bf16 MFMA GEMM.  C = act(A@W + bias), A=Ahi+Alo, W=Whi+Wlo.
// Storage layout everywhere: K8-chunked  arr[k/8][row][8]  (16B per row-chunk).
//   A: [K/8][M][8] (row=m), W: [K/8][N][8] (row=n, i.e. W^T), C: [N/8][M][8].
// 128x128 tile, 256 thr = 4 waves, each wave 64x64 via 4x4 mfma_16x16x32 tiles.
// 3 MFMAs per tile per k-step: Ahi*Whi + Ahi*Wlo + Alo*Whi  (~2^-16 rel err).
// ---------------------------------------------------------------------------
__global__ __launch_bounds__(256) void gemm_mfma(
    const u16* __restrict__ Ahi, const u16* __restrict__ Alo,
    const u16* __restrict__ Whi, const u16* __restrict__ Wlo,
    const float* __restrict__ bias,
    u16* __restrict__ Chi, u16* __restrict__ Clo,
    int M, int K, int N, int relu)
{
    __shared__ u16 sAh[4096], sAl[4096], sWh[4096], sWl[4096];   // 8KB each
    const int tid = threadIdx.x;
    const int w = tid >> 6, lane = tid & 63;
    const int wr = w >> 1, wc = w & 1;          // wave's 64x64 quadrant
    const int m0 = blockIdx.y * 128, n0 = blockIdx.x * 128;
    const int ml = lane & 15, q = lane >> 4;

    f32x4 acc[4][4];
#pragma unroll
    for (int i = 0; i < 4; ++i)
#pragma unroll
        for (int j = 0; j < 4; ++j)
#pragma unroll
            for (int r = 0; r < 4; ++r) acc[i][j][r] = 0.f;

    const int nIter = K >> 5;                    // BK = 32 = 4 chunks of 8
    for (int it = 0; it < nIter; ++it) {
        const int c = it * 4 + w;                // this wave stages chunk c
#pragma unroll
        for (int h = 0; h < 2; ++h) {            // 64 rows per instruction
            const size_t ga = ((size_t)c * M + m0 + h * 64 + lane) * 8;
            const size_t gw = ((size_t)c * N + n0 + h * 64 + lane) * 8;
            GLD16(Ahi + ga, sAh + w * 1024 + h * 512);
            GLD16(Alo + ga, sAl + w * 1024 + h * 512);
            GLD16(Whi + gw, sWh + w * 1024 + h * 512);
            GLD16(Wlo + gw, sWl + w * 1024 + h * 512);
        }
        __syncthreads();

        // fragment loads: lane (ml, q) reads row (tileBase+ml), k-chunk q -> b128
        const int ab = q * 1024 + wr * 512 + ml * 8;
        const int bb = q * 1024 + wc * 512 + ml * 8;
        bf16x8 ah[4], al[4], bh[4], bl[4];
#pragma unroll
        for (int t = 0; t < 4; ++t) {
            ah[t] = *(const bf16x8*)&sAh[ab + t * 128];
            al[t] = *(const bf16x8*)&sAl[ab + t * 128];
            bh[t] = *(const bf16x8*)&sWh[bb + t * 128];
            bl[t] = *(const bf16x8*)&sWl[bb + t * 128];
        }
#pragma unroll
        for (int i = 0; i < 4; ++i)
#pragma unroll
            for (int j = 0; j < 4; ++j) {
                f32x4 a = acc[i][j];
                a = __builtin_amdgcn_mfma_f32_16x16x32_bf16(al[i], bh[j], a, 0, 0, 0);
                a = __builtin_amdgcn_mfma_f32_16x16x32_bf16(ah[i], bl[j], a, 0, 0, 0);
                a = __builtin_amdgcn_mfma_f32_16x16x32_bf16(ah[i], bh[j], a, 0, 0, 0);
                acc[i][j] = a;
            }
        __syncthreads();
    }

    // epilogue: bias + relu, split to hi/lo, store K8-chunked [N/8][M][8]
#pragma unroll
    for (int j = 0; j < 4; ++j) {
        const int n = n0 + wc * 64 + j * 16 + ml;
        const float bs = bias[n];
        const size_t cb = (size_t)(n >> 3) * M * 8 + (n & 7);
#pragma unroll
        for (int i = 0; i < 4; ++i) {
            const int mbase = m0 + wr * 64 + i * 16 + q * 4;
#pragma unroll
            for (int r = 0; r < 4; ++r) {
                float x = acc[i][j][r] + bs;
                if (relu) x = fmaxf(x, 0.f);
                u16 hi, lo; fsplit(x, hi, lo);
                const size_t off = cb + (size_t)(mbase + r) * 8;
                Chi[off] = hi; Clo[off] = lo;
            }
        }
    }
}

// ---------------------------------------------------------------------------
// fp32 KxN weight -> K8-chunked W^T hi/lo  ([Kpad/8][N][8]), zero pad k>=Kreal
// ---------------------------------------------------------------------------
__global__ void conv_w(const float* __restrict__ W, u16* __restrict__ Whi,
                       u16* __restrict__ Wlo, int Kreal, int Kpad, int N)
{
    const int idx = blockIdx.x * 256 + threadIdx.x;   // one per (c, n)
    if (idx >= (Kpad >> 3) * N) return;
    const int c = idx / N, n = idx - c * N;
#pragma unroll
    for (int j = 0; j < 8; ++j) {
        const int k = c * 8 + j;
        const float x = (k < Kreal) ? W[(size_t)k * N + n] : 0.f;
        u16 hi, lo; fsplit(x, hi, lo);
        Whi[(size_t)idx * 8 + j] = hi;
        Wlo[(size_t)idx * 8 + j] = lo;
    }
}

// dense (BATCH x 13 fp32) -> K8-chunked hi/lo [4][BATCH][8], zero pad k>=13
__global__ void conv_dense(const float* __restrict__ dense,
                           u16* __restrict__ Dhi, u16* __restrict__ Dlo)
{
    const int m = blockIdx.x * 256 + threadIdx.x;
    float v[13];
#pragma unroll
    for (int j = 0; j < 13; ++j) v[j] = dense[(size_t)m * 13 + j];
#pragma unroll
    for (int cc = 0; cc < 4; ++cc) {
        const size_t base = ((size_t)cc * BATCH + m) * 8;
#pragma unroll
        for (int j = 0; j < 8; ++j) {
            const int k = cc * 8 + j;
            const float x = (k < 13) ? v[k] : 0.f;
            u16 hi, lo; fsplit(x, hi, lo);
            Dhi[base + j] = hi; Dlo[base + j] = lo;
        }
    }
}

// ---------------------------------------------------------------------------
// Interaction v2 — LDS-free, MFMA Gram.
// One wave per sample. mfma_f32_32x32x16_bf16: A-frag (row=lane&31,
// k=(lane>>5)*8+j) and B-frag (col=lane&31, same k) have IDENTICAL (lane,reg)
// mappings for A.A^T, so one fragment feeds both operands.
// Lane row r = lane&31:  r=0 -> h (already hi/lo-split in X chunks 0..15),
// r=1..26 -> emb gather (fp32 -> fsplit), r>=27 -> zero.
// 8 k-steps (K=128) x 3 hi/lo MFMAs. Epilogue scatters triu hi/lo into X
// chunks 16..63 (k=128..505) + zero pad 506..511.
// ---------------------------------------------------------------------------
__global__ __launch_bounds__(256) void interact_kernel(
    u16* __restrict__ Xhi, u16* __restrict__ Xlo,
    const int* __restrict__ sidx, const float* __restrict__ emb)
{
    const int wave = threadIdx.x >> 6, lane = threadIdx.x & 63;
    const int b = blockIdx.x * 4 + wave;
    const int r = lane & 31, half = lane >> 5;

    bf16x8 fh[8], fl[8];

    if (r == 0) {
        // h: load hi/lo directly from X chunk layout [k/8][BATCH][8]
#pragma unroll
        for (int s = 0; s < 8; ++s) {
            const size_t base = ((size_t)(2 * s + half) * BATCH + b) * 8;
            fh[s] = *(const bf16x8*)&Xhi[base];
            fl[s] = *(const bf16x8*)&Xlo[base];
        }
    } else if (r <= NSP) {
        const int ix = sidx[(size_t)b * NSP + (r - 1)] & VOCAB_MASK;
        const float* ep = emb + (size_t)ix * 128 + half * 8;
        float4 v[8][2];
#pragma unroll
        for (int s = 0; s < 8; ++s) {           // all 16 loads in flight
            v[s][0] = *(const float4*)(ep + s * 16);
            v[s][1] = *(const float4*)(ep + s * 16 + 4);
        }
#pragma unroll
        for (int s = 0; s < 8; ++s) {
            const float f[8] = {v[s][0].x, v[s][0].y, v[s][0].z, v[s][0].w,
                                v[s][1].x, v[s][1].y, v[s][1].z, v[s][1].w};
#pragma unroll
            for (int j = 0; j < 8; ++j) {
                u16 hi, lo; fsplit(f[j], hi, lo);
                fh[s][j] = u2b(hi); fl[s][j] = u2b(lo);
            }
        }
    } else {
#pragma unroll
        for (int s = 0; s < 8; ++s) {
#pragma unroll
            for (int j = 0; j < 8; ++j) { fh[s][j] = u2b(0); fl[s][j] = u2b(0); }
        }
    }

    f32x16 acc = {};
#pragma unroll
    for (int s = 0; s < 8; ++s) {
        acc = __builtin_amdgcn_mfma_f32_32x32x16_bf16(fl[s], fh[s], acc, 0, 0, 0);
        acc = __builtin_amdgcn_mfma_f32_32x32x16_bf16(fh[s], fl[s], acc, 0, 0, 0);
        acc = __builtin_amdgcn_mfma_f32_32x32x16_bf16(fh[s], fh[s], acc, 0, 0, 0);
    }

    // C layout: col = lane&31, row = (reg&3) + 8*(reg>>2) + 4*(lane>>5)
    const int col = lane & 31;
    if (col < NROW) {
#pragma unroll
        for (int reg = 0; reg < 16; ++reg) {
            const int row = (reg & 3) + 8 * (reg >> 2) + 4 * half;
            if (row > col) continue;            // need row <= col < 27
            const int k = 128 + row * NROW - (row * (row - 1)) / 2 - row + col;
            u16 hi, lo; fsplit(acc[reg], hi, lo);
            const size_t off = ((size_t)(k >> 3) * BATCH + b) * 8 + (k & 7);
            Xhi[off] = hi; Xlo[off] = lo;
        }
    }
    if (lane < 6) {                             // zero pad k = 506..511
        const int k = 506 + lane;
        const size_t off = ((size_t)(k >> 3) * BATCH + b) * 8 + (k & 7);
        Xhi[off] = 0; Xlo[off] = 0;
    }
}

// ---------------------------------------------------------------------------
// Final layer: out[b] = dot(A[b][:256], w) + bias.  A is K8-chunked hi/lo.
// One wave per sample: lanes 0..31 do hi chunks, 32..63 lo chunks.
// ---------------------------------------------------------------------------
__global__ __launch_bounds__(256) void final_dot(
    const u16* __restrict__ Ahi, const u16* __restrict__ Alo,
    const float* __restrict__ wv, const float* __restrict__ bias,
    float* __restrict__ out)
{
    const int wave = threadIdx.x >> 6, lane = threadIdx.x & 63;
    const int b = blockIdx.x * 4 + wave;
    const int c = lane & 31;
    const u16* src = (lane >= 32) ? Alo : Ahi;
    const size_t base = ((size_t)c * BATCH + b) * 8;
    float s = 0.f;
#pragma unroll
    for (int j = 0; j < 8; ++j) s += bf2f(src[base + j]) * wv[c * 8 + j];
#pragma unroll
    for (int off = 32; off > 0; off >>= 1) s += __shfl_down(s, off);
    if (lane == 0) out[b] = s + bias[0];
}

// ---------------------------------------------------------------------------
extern "C" void kernel_launch(void* const* d_in, const int* in_sizes, int n_in,
                              void* d_out, int out_size, void* d_ws, size_t ws_size,
                              hipStream_t stream)
{
    const float* dense = (const float*)d_in[0];
    const int*   sidx  = (const int*)d_in[1];
    const float* emb   = (const float*)d_in[2];
    const float* bw0 = (const float*)d_in[3],  *bb0 = (const float*)d_in[4];
    const float* bw1 = (const float*)d_in[5],  *bb1 = (const float*)d_in[6];
    const float* bw2 = (const float*)d_in[7],  *bb2 = (const float*)d_in[8];
    const float* tw0 = (const float*)d_in[9],  *tb0 = (const float*)d_in[10];
    const float* tw1 = (const float*)d_in[11], *tb1 = (const float*)d_in[12];
    const float* tw2 = (const float*)d_in[13], *tb2 = (const float*)d_in[14];
    const float* tw3 = (const float*)d_in[15], *tb3 = (const float*)d_in[16];
    const float* tw4 = (const float*)d_in[17], *tb4 = (const float*)d_in[18];
    float* out = (float*)d_out;

    // ---- workspace carve-up (~555 MB)
    char* p = (char*)d_ws;
    const size_t ACT = (size_t)BATCH * 1024 * sizeof(u16);   // 134 MB
    u16* Xhi = (u16*)p; p += ACT;
    u16* Xlo = (u16*)p; p += ACT;
    u16* Yhi = (u16*)p; p += ACT;
    u16* Ylo = (u16*)p; p += ACT;
    u16* D0hi = (u16*)p; p += (size_t)BATCH * 32 * sizeof(u16);
    u16* D0lo = (u16*)p; p += (size_t)BATCH * 32 * sizeof(u16);
    auto alloc_w = [&](size_t elems, u16** hi, u16** lo) {
        *hi = (u16*)p; p += elems * sizeof(u16);
        *lo = (u16*)p; p += elems * sizeof(u16);
    };
    u16 *W0h,*W0l,*W1h,*W1l,*W2h,*W2l,*T0h,*T0l,*T1h,*T1l,*T2h,*T2l,*T3h,*T3l;
    alloc_w(32 * 512, &W0h, &W0l);
    alloc_w(512 * 256, &W1h, &W1l);
    alloc_w(256 * 128, &W2h, &W2l);
    alloc_w(512 * 1024, &T0h, &T0l);
    alloc_w(1024 * 1024, &T1h, &T1l);
    alloc_w(1024 * 512, &T2h, &T2l);
    alloc_w(512 * 256, &T3h, &T3l);

    const dim3 blk(256);
    auto cwg = [](int kpad, int n) { return dim3(((kpad >> 3) * n + 255) / 256); };

    // ---- convert inputs to hi/lo chunked bf16
    conv_dense<<<BATCH / 256, blk, 0, stream>>>(dense, D0hi, D0lo);
    conv_w<<<cwg(32, 512),    blk, 0, stream>>>(bw0, W0h, W0l, 13,   32,   512);
    conv_w<<<cwg(512, 256),   blk, 0, stream>>>(bw1, W1h, W1l, 512,  512,  256);
    conv_w<<<cwg(256, 128),   blk, 0, stream>>>(bw2, W2h, W2l, 256,  256,  128);
    conv_w<<<cwg(512, 1024),  blk, 0, stream>>>(tw0, T0h, T0l, 506,  512,  1024);
    conv_w<<<cwg(1024, 1024), blk, 0, stream>>>(tw1, T1h, T1l, 1024, 1024, 1024);
    conv_w<<<cwg(1024, 512),  blk, 0, stream>>>(tw2, T2h, T2l, 1024, 1024, 512);
    conv_w<<<cwg(512, 256),   blk, 0, stream>>>(tw3, T3h, T3l, 512,  512,  256);

    // ---- bottom MLP (13->512->256->128); L2 lands in X chunks 0..15 (= h)
    gemm_mfma<<<dim3(4, 512), blk, 0, stream>>>(D0hi, D0lo, W0h, W0l, bb0, Xhi, Xlo, BATCH, 32,  512, 1);
    gemm_mfma<<<dim3(2, 512), blk, 0, stream>>>(Xhi, Xlo, W1h, W1l, bb1, Yhi, Ylo, BATCH, 512, 256, 1);
    gemm_mfma<<<dim3(1, 512), blk, 0, stream>>>(Yhi, Ylo, W2h, W2l, bb2, Xhi, Xlo, BATCH, 256, 128, 1);

    // ---- interaction fills X chunks 16..63 (triu + pad), no LDS
    interact_kernel<<<dim3(BATCH / 4), blk, 0, stream>>>(Xhi, Xlo, sidx, emb);

    // ---- top MLP (506(512)->1024->1024->512->256->1)
    gemm_mfma<<<dim3(8, 512), blk, 0, stream>>>(Xhi, Xlo, T0h, T0l, tb0, Yhi, Ylo, BATCH, 512,  1024, 1);
    gemm_mfma<<<dim3(8, 512), blk, 0, stream>>>(Yhi, Ylo, T1h, T1l, tb1, Xhi, Xlo, BATCH, 1024, 1024, 1);
    gemm_mfma<<<dim3(4, 512), blk, 0, stream>>>(Xhi, Xlo, T2h, T2l, tb2, Yhi, Ylo, BATCH, 1024, 512,  1);
    gemm_mfma<<<dim3(2, 512), blk, 0, stream>>>(Yhi, Ylo, T3h, T3l, tb3, Xhi, Xlo, BATCH, 512,  256,  1);
    final_dot<<<dim3(BATCH / 4), blk, 0, stream>>>(Xhi, Xlo, tw4, tb4, out);
}